// Round 1
// baseline (860.438 us; speedup 1.0000x reference)
//
#include <hip/hip_runtime.h>
#include <math.h>

namespace {

constexpr int kNME  = 262144;
constexpr int kKE   = 64;
constexpr int kNDOF = 524288;
constexpr int kNNZ  = kNME * kKE;

constexpr float kEmin    = 1e-9f;
constexpr float kEmax    = 1.0f;
constexpr float kVolfrac = 0.4f;

// ---------------------------------------------------------------------------
// Kernel 1: per-element SIMP scale + rho partial sum.
// scale[e] = Emin + sigmoid(W_x[e])^3 * (Emax - Emin)
// ---------------------------------------------------------------------------
__global__ void scale_kernel(const float* __restrict__ W_x,
                             float* __restrict__ scale,
                             float* __restrict__ rho_sum) {
    int i = blockIdx.x * blockDim.x + threadIdx.x;
    float rho = 0.0f;
    if (i < kNME) {
        float x = W_x[i];
        rho = 1.0f / (1.0f + __expf(-x));
        float s = kEmin + rho * rho * rho * (kEmax - kEmin);
        scale[i] = s;
    }
    // wave64 reduction of rho
    for (int off = 32; off > 0; off >>= 1) rho += __shfl_down(rho, off, 64);
    __shared__ float partial[4];  // blockDim.x == 256 -> 4 waves
    const int lane = threadIdx.x & 63;
    const int wid  = threadIdx.x >> 6;
    if (lane == 0) partial[wid] = rho;
    __syncthreads();
    if (threadIdx.x == 0) {
        float t = partial[0] + partial[1] + partial[2] + partial[3];
        atomicAdd(rho_sum, t);
    }
}

// ---------------------------------------------------------------------------
// Kernel 2: COO scatter  Ku[rows[i]] += K_sep[i] * scale[i/64] * u[cols[i]]
// ---------------------------------------------------------------------------
__global__ void scatter_kernel(const float* __restrict__ K_sep,
                               const int*   __restrict__ rows,
                               const int*   __restrict__ cols,
                               const float* __restrict__ u,
                               const float* __restrict__ scale,
                               float* __restrict__ Ku) {
    int i = blockIdx.x * blockDim.x + threadIdx.x;
    if (i >= kNNZ) return;
    float s = scale[i >> 6];           // 64 consecutive threads share one scale
    float v = K_sep[i] * s * u[cols[i]];
    atomicAdd(&Ku[rows[i]], v);
}

// ---------------------------------------------------------------------------
// Kernel 3: sum of (Ku - f)^2
// ---------------------------------------------------------------------------
__global__ void norm_kernel(const float* __restrict__ Ku,
                            const float* __restrict__ f,
                            float* __restrict__ norm_sum) {
    float acc = 0.0f;
    for (int i = blockIdx.x * blockDim.x + threadIdx.x; i < kNDOF;
         i += gridDim.x * blockDim.x) {
        float d = Ku[i] - f[i];
        acc += d * d;
    }
    for (int off = 32; off > 0; off >>= 1) acc += __shfl_down(acc, off, 64);
    __shared__ float partial[4];
    const int lane = threadIdx.x & 63;
    const int wid  = threadIdx.x >> 6;
    if (lane == 0) partial[wid] = acc;
    __syncthreads();
    if (threadIdx.x == 0) {
        float t = partial[0] + partial[1] + partial[2] + partial[3];
        atomicAdd(norm_sum, t);
    }
}

// ---------------------------------------------------------------------------
// Kernel 4: finalize scalar loss
// ---------------------------------------------------------------------------
__global__ void finalize_kernel(const float* __restrict__ acc,
                                float* __restrict__ out) {
    if (threadIdx.x == 0 && blockIdx.x == 0) {
        float rho_mean = acc[0] * (1.0f / (float)kNME);
        float vol = fmaxf(rho_mean - kVolfrac, 0.0f);
        out[0] = vol + sqrtf(acc[1]);
    }
}

}  // namespace

extern "C" void kernel_launch(void* const* d_in, const int* in_sizes, int n_in,
                              void* d_out, int out_size, void* d_ws, size_t ws_size,
                              hipStream_t stream) {
    const float* W_x   = (const float*)d_in[0];
    const float* K_sep = (const float*)d_in[1];
    const int*   idx   = (const int*)d_in[2];   // (2, NNZ) row-major
    const float* u     = (const float*)d_in[3];
    const float* f     = (const float*)d_in[4];
    const int* rows = idx;
    const int* cols = idx + kNNZ;

    float* ws    = (float*)d_ws;
    float* Ku    = ws;                   // kNDOF floats
    float* scale = ws + kNDOF;           // kNME floats
    float* acc   = ws + kNDOF + kNME;    // acc[0] = rho_sum, acc[1] = norm_sum

    // Zero Ku + scale + accumulators (replay-safe: done every call).
    hipMemsetAsync(d_ws, 0, (size_t)(kNDOF + kNME + 2) * sizeof(float), stream);

    scale_kernel<<<(kNME + 255) / 256, 256, 0, stream>>>(W_x, scale, acc);

    scatter_kernel<<<(kNNZ + 255) / 256, 256, 0, stream>>>(K_sep, rows, cols, u,
                                                           scale, Ku);

    norm_kernel<<<2048, 256, 0, stream>>>(Ku, f, acc + 1);

    finalize_kernel<<<1, 64, 0, stream>>>(acc, (float*)d_out);
}